// Round 2
// baseline (775.795 us; speedup 1.0000x reference)
//
#include <hip/hip_runtime.h>

// ---------------------------------------------------------------------------
// GCN 2-layer forward on MI355X.
// NOTE: harness passes integer inputs as int32 (edge_index int64 in the
// reference arrives as int32 on device). Round-0 crash was casting it to
// long long -> OOB reads.
//
// Pipeline per call (d_ws re-poisoned between calls, so rebuild everything):
//   1. cnt[v] = 1 (self loop) ; cnt[col[e]] += 1          (int atomics)
//   2. offsets = exclusive_scan(cnt)  (3-kernel scan)      ; dinv = rsqrt(cnt)
//   3. fill CSR: for each message (edge + self loop) slot = cursor[col]++,
//      csr_src[slot] = row, csr_norm[slot] = dinv[row]*dinv[col]
//   4. H1 = x @ W1                      (wave-per-row GEMM, W in LDS)
//   5. A1 = relu(segsum(norm*H1[row] -> col) + b1)  (wave-per-node gather)
//   6. H2 = A1 @ W2
//   7. out = segsum(norm*H2[row] -> col) + b2
// ---------------------------------------------------------------------------

__global__ void k_init_cnt(int* __restrict__ cnt, int N) {
    int v = blockIdx.x * blockDim.x + threadIdx.x;
    if (v < N) cnt[v] = 1;  // self loop
}

__global__ void k_count(const int* __restrict__ col, int E, int* __restrict__ cnt) {
    int i = blockIdx.x * blockDim.x + threadIdx.x;
    int stride = gridDim.x * blockDim.x;
    for (; i < E; i += stride) {
        atomicAdd(&cnt[col[i]], 1);
    }
}

// Per-chunk (1024 elements) sums for the scan.
__global__ void k_blocksum(const int* __restrict__ cnt, int N, int* __restrict__ bsum) {
    __shared__ int sh[256];
    int base = blockIdx.x * 1024;
    int t = threadIdx.x;
    int s = 0;
    #pragma unroll
    for (int j = 0; j < 4; j++) {
        int v = base + t + j * 256;
        if (v < N) s += cnt[v];
    }
    sh[t] = s;
    __syncthreads();
    for (int d = 128; d > 0; d >>= 1) {
        if (t < d) sh[t] += sh[t + d];
        __syncthreads();
    }
    if (t == 0) bsum[blockIdx.x] = sh[0];
}

// Exclusive scan of the (<=1024) chunk sums, single block.
__global__ void k_scan_bsum(int* __restrict__ bsum, int B) {
    __shared__ int sh[1024];
    int t = threadIdx.x;
    for (int i = t; i < B; i += blockDim.x) sh[i] = bsum[i];
    __syncthreads();
    if (t == 0) {
        int run = 0;
        for (int i = 0; i < B; i++) { int v = sh[i]; sh[i] = run; run += v; }
    }
    __syncthreads();
    for (int i = t; i < B; i += blockDim.x) bsum[i] = sh[i];
}

// Per-chunk exclusive scan -> offsets; also cursor init and dinv.
__global__ void k_scan_chunks(const int* __restrict__ cnt, int N,
                              const int* __restrict__ bsum,
                              int* __restrict__ offsets, int* __restrict__ cursor,
                              float* __restrict__ dinv) {
    __shared__ int wsum[4];
    int base = blockIdx.x * 1024;
    int t = threadIdx.x;
    int lane = t & 63, wid = t >> 6;
    int vals[4];
    int s = 0;
    #pragma unroll
    for (int j = 0; j < 4; j++) {
        int v = base + t * 4 + j;
        int c = (v < N) ? cnt[v] : 0;
        vals[j] = c;
        s += c;
    }
    // inclusive scan of per-thread sums within the wave
    int sc = s;
    #pragma unroll
    for (int d = 1; d < 64; d <<= 1) {
        int o = __shfl_up(sc, d);
        if (lane >= d) sc += o;
    }
    if (lane == 63) wsum[wid] = sc;
    __syncthreads();
    int woff = 0;
    for (int i = 0; i < wid; i++) woff += wsum[i];
    int run = bsum[blockIdx.x] + woff + (sc - s);  // exclusive prefix for this thread
    #pragma unroll
    for (int j = 0; j < 4; j++) {
        int v = base + t * 4 + j;
        if (v < N) {
            offsets[v] = run;
            cursor[v] = run;
            dinv[v] = rsqrtf((float)vals[j]);  // cnt >= 1 always (self loop)
        }
        run += vals[j];
    }
}

__global__ void k_fill(const int* __restrict__ rowi, const int* __restrict__ coli,
                       int E, int N, int* __restrict__ cursor, const float* __restrict__ dinv,
                       int* __restrict__ csrc, float* __restrict__ cnorm) {
    int i = blockIdx.x * blockDim.x + threadIdx.x;
    int stride = gridDim.x * blockDim.x;
    int T = E + N;
    for (; i < T; i += stride) {
        int r, c;
        if (i < E) { r = rowi[i]; c = coli[i]; }
        else       { r = i - E; c = r; }  // self loop
        int slot = atomicAdd(&cursor[c], 1);
        csrc[slot] = r;
        cnorm[slot] = dinv[r] * dinv[c];
    }
}

// H[row] = X[row] @ W   (64x64 W staged in LDS; one wave per row, lane = out feature)
__global__ __launch_bounds__(256) void k_gemm(const float* __restrict__ X,
                                              const float* __restrict__ W,
                                              float* __restrict__ H, int N) {
    __shared__ float Ws[64 * 64];
    int t = threadIdx.x;
    const float4* W4 = (const float4*)W;
    float4* Ws4 = (float4*)Ws;
    for (int i = t; i < 1024; i += 256) Ws4[i] = W4[i];
    __syncthreads();
    int lane = t & 63, wid = t >> 6;
    int row = blockIdx.x * 4 + wid;
    if (row >= N) return;
    float xv = X[(size_t)row * 64 + lane];
    float acc = 0.f;
    #pragma unroll
    for (int k = 0; k < 64; k++) {
        float xk = __shfl(xv, k);
        acc = fmaf(xk, Ws[k * 64 + lane], acc);
    }
    H[(size_t)row * 64 + lane] = acc;
}

// out[v] = (relu?)( sum_{j in CSR[v]} norm_j * H[src_j] + bias )
template <bool RELU>
__global__ __launch_bounds__(256) void k_aggregate(const float* __restrict__ H,
                                                   const int* __restrict__ offsets,
                                                   const int* __restrict__ cnt,
                                                   const int* __restrict__ csrc,
                                                   const float* __restrict__ cnorm,
                                                   const float* __restrict__ bias,
                                                   float* __restrict__ out, int N) {
    int t = threadIdx.x;
    int lane = t & 63, wid = t >> 6;
    int v = blockIdx.x * 4 + wid;
    if (v >= N) return;
    int beg = offsets[v];
    int end = beg + cnt[v];
    float acc = 0.f;
    int j = beg;
    if (j < end) {
        int s = csrc[j];
        float w = cnorm[j];
        for (; j + 1 < end; j++) {
            int s2 = csrc[j + 1];      // prefetch next edge's metadata
            float w2 = cnorm[j + 1];
            acc = fmaf(w, H[(size_t)s * 64 + lane], acc);
            s = s2; w = w2;
        }
        acc = fmaf(w, H[(size_t)s * 64 + lane], acc);
    }
    acc += bias[lane];
    if (RELU) acc = fmaxf(acc, 0.f);
    out[(size_t)v * 64 + lane] = acc;
}

extern "C" void kernel_launch(void* const* d_in, const int* in_sizes, int n_in,
                              void* d_out, int out_size, void* d_ws, size_t ws_size,
                              hipStream_t stream) {
    const float* x   = (const float*)d_in[0];
    const int*   ei  = (const int*)d_in[1];    // int32 on device (harness converts)
    const float* W1  = (const float*)d_in[2];
    const float* b1  = (const float*)d_in[3];
    const float* W2  = (const float*)d_in[4];
    const float* b2  = (const float*)d_in[5];
    float* out       = (float*)d_out;

    const int N = in_sizes[0] / 64;
    const int E = in_sizes[1] / 2;
    const int* row = ei;
    const int* col = ei + E;
    const int T = E + N;

    // Workspace layout (256B-aligned slices), total ~66 MB
    char* p = (char*)d_ws;
    auto alloc = [&](size_t bytes) { void* r = (void*)p; p += (bytes + 255) & ~(size_t)255; return r; };
    int*   cnt     = (int*)alloc((size_t)N * 4);
    int*   offsets = (int*)alloc((size_t)N * 4);
    int*   cursor  = (int*)alloc((size_t)N * 4);
    int*   bsum    = (int*)alloc(1024 * 4);
    float* dinv    = (float*)alloc((size_t)N * 4);
    int*   csrc    = (int*)alloc((size_t)T * 4);
    float* cnorm   = (float*)alloc((size_t)T * 4);
    float* hbuf    = (float*)alloc((size_t)N * 64 * 4);
    float* abuf    = (float*)alloc((size_t)N * 64 * 4);

    const int B = (N + 1023) / 1024;  // scan chunks

    k_init_cnt<<<(N + 255) / 256, 256, 0, stream>>>(cnt, N);
    k_count<<<2048, 256, 0, stream>>>(col, E, cnt);
    k_blocksum<<<B, 256, 0, stream>>>(cnt, N, bsum);
    k_scan_bsum<<<1, 256, 0, stream>>>(bsum, B);
    k_scan_chunks<<<B, 256, 0, stream>>>(cnt, N, bsum, offsets, cursor, dinv);
    k_fill<<<2048, 256, 0, stream>>>(row, col, E, N, cursor, dinv, csrc, cnorm);

    const int GB = (N + 3) / 4;  // 4 waves/block, wave per row/node
    k_gemm<<<GB, 256, 0, stream>>>(x, W1, hbuf, N);
    k_aggregate<true><<<GB, 256, 0, stream>>>(hbuf, offsets, cnt, csrc, cnorm, b1, abuf, N);
    k_gemm<<<GB, 256, 0, stream>>>(abuf, W2, hbuf, N);
    k_aggregate<false><<<GB, 256, 0, stream>>>(hbuf, offsets, cnt, csrc, cnorm, b2, out, N);
}

// Round 3
// 588.068 us; speedup vs baseline: 1.3192x; 1.3192x over previous
//
#include <hip/hip_runtime.h>

// ---------------------------------------------------------------------------
// GCN 2-layer forward, round 3.
//   - Intermediate features stored as packed bf16 (row = 32 uints = 128 B):
//     halves gather bytes/edge (256->128 B). Accumulation stays fp32.
//   - norm folded out of edge stream: H' = dinv[row]*(X W); epilogue *dinv[col].
//     cnorm array eliminated -> k_fill writes only csrc.
//   - Aggregate: wave per node, quarter-wave (16 lanes x uint2) per edge ->
//     4 edges in flight/iteration, shfl_xor(16,32) reduction.
// ---------------------------------------------------------------------------

#define WPB 4  // waves per block

__device__ __forceinline__ unsigned bf16_rne(float f) {
    unsigned b = __float_as_uint(f);
    return (b + 0x7fffu + ((b >> 16) & 1u)) >> 16;
}
__device__ __forceinline__ float bf16_lo(unsigned u) { return __uint_as_float(u << 16); }
__device__ __forceinline__ float bf16_hi(unsigned u) { return __uint_as_float(u & 0xffff0000u); }

__global__ void k_init_cnt(int* __restrict__ cnt, int N) {
    int v = blockIdx.x * blockDim.x + threadIdx.x;
    if (v < N) cnt[v] = 1;  // self loop
}

__global__ void k_count(const int4* __restrict__ col4, int E4, int* __restrict__ cnt) {
    int i = blockIdx.x * blockDim.x + threadIdx.x;
    int stride = gridDim.x * blockDim.x;
    for (; i < E4; i += stride) {
        int4 c = col4[i];
        atomicAdd(&cnt[c.x], 1);
        atomicAdd(&cnt[c.y], 1);
        atomicAdd(&cnt[c.z], 1);
        atomicAdd(&cnt[c.w], 1);
    }
}

__global__ void k_blocksum(const int* __restrict__ cnt, int N, int* __restrict__ bsum) {
    __shared__ int sh[256];
    int base = blockIdx.x * 1024;
    int t = threadIdx.x;
    int s = 0;
    #pragma unroll
    for (int j = 0; j < 4; j++) {
        int v = base + t + j * 256;
        if (v < N) s += cnt[v];
    }
    sh[t] = s;
    __syncthreads();
    for (int d = 128; d > 0; d >>= 1) {
        if (t < d) sh[t] += sh[t + d];
        __syncthreads();
    }
    if (t == 0) bsum[blockIdx.x] = sh[0];
}

__global__ void k_scan_bsum(int* __restrict__ bsum, int B) {
    __shared__ int sh[1024];
    int t = threadIdx.x;
    for (int i = t; i < B; i += blockDim.x) sh[i] = bsum[i];
    __syncthreads();
    if (t == 0) {
        int run = 0;
        for (int i = 0; i < B; i++) { int v = sh[i]; sh[i] = run; run += v; }
    }
    __syncthreads();
    for (int i = t; i < B; i += blockDim.x) bsum[i] = sh[i];
}

__global__ void k_scan_chunks(const int* __restrict__ cnt, int N,
                              const int* __restrict__ bsum,
                              int* __restrict__ offsets, int* __restrict__ cursor,
                              float* __restrict__ dinv) {
    __shared__ int wsum[4];
    int base = blockIdx.x * 1024;
    int t = threadIdx.x;
    int lane = t & 63, wid = t >> 6;
    int vals[4];
    int s = 0;
    #pragma unroll
    for (int j = 0; j < 4; j++) {
        int v = base + t * 4 + j;
        int c = (v < N) ? cnt[v] : 0;
        vals[j] = c;
        s += c;
    }
    int sc = s;
    #pragma unroll
    for (int d = 1; d < 64; d <<= 1) {
        int o = __shfl_up(sc, d);
        if (lane >= d) sc += o;
    }
    if (lane == 63) wsum[wid] = sc;
    __syncthreads();
    int woff = 0;
    for (int i = 0; i < wid; i++) woff += wsum[i];
    int run = bsum[blockIdx.x] + woff + (sc - s);
    #pragma unroll
    for (int j = 0; j < 4; j++) {
        int v = base + t * 4 + j;
        if (v < N) {
            offsets[v] = run;
            cursor[v] = run;
            dinv[v] = rsqrtf((float)vals[j]);  // cnt >= 1 (self loop)
        }
        run += vals[j];
    }
}

__global__ void k_fill(const int* __restrict__ rowi, const int* __restrict__ coli,
                       int E, int N, int* __restrict__ cursor,
                       int* __restrict__ csrc) {
    int i = blockIdx.x * blockDim.x + threadIdx.x;
    int stride = gridDim.x * blockDim.x;
    int T = E + N;
    for (; i < T; i += stride) {
        int r, c;
        if (i < E) { r = rowi[i]; c = coli[i]; }
        else       { r = i - E; c = r; }  // self loop
        int slot = atomicAdd(&cursor[c], 1);
        csrc[slot] = r;
    }
}

// H[row] = dinv[row] * (X[row] @ W), output packed bf16 (32 uints/row).
// One wave per row, many rows per wave (W staged once per block).
template <bool BF16IN>
__global__ __launch_bounds__(256) void k_gemm(const void* __restrict__ Xv,
                                              const float* __restrict__ W,
                                              const float* __restrict__ dinv,
                                              unsigned* __restrict__ Hout,
                                              int N, int totalWaves) {
    __shared__ float Ws[64 * 64];
    int t = threadIdx.x;
    {
        const float4* W4 = (const float4*)W;
        float4* Ws4 = (float4*)Ws;
        for (int i = t; i < 1024; i += 256) Ws4[i] = W4[i];
    }
    __syncthreads();
    int lane = t & 63;
    int wave = blockIdx.x * WPB + (t >> 6);
    for (int row = wave; row < N; row += totalWaves) {
        float f0, f1 = 0.f;
        if (BF16IN) {
            const unsigned* A = (const unsigned*)Xv;
            unsigned u = A[(size_t)row * 32 + (lane & 31)];
            f0 = bf16_lo(u); f1 = bf16_hi(u);
        } else {
            const float* X = (const float*)Xv;
            f0 = X[(size_t)row * 64 + lane];
        }
        float acc = 0.f;
        #pragma unroll
        for (int k = 0; k < 64; k++) {
            float xk = BF16IN ? __shfl((k & 1) ? f1 : f0, k >> 1)
                              : __shfl(f0, k);
            acc = fmaf(xk, Ws[k * 64 + lane], acc);
        }
        float val = acc * dinv[row];
        float p0 = __shfl(val, (lane & 31) * 2);
        float p1 = __shfl(val, (lane & 31) * 2 + 1);
        if (lane < 32) {
            Hout[(size_t)row * 32 + lane] = bf16_rne(p0) | (bf16_rne(p1) << 16);
        }
    }
}

// out[v] = epi( dinv[v] * sum_{j in CSR[v]} H[src_j] + bias )
// Wave per node; quarter-wave (16 lanes x uint2 = 128 B) per edge, 4 edges/iter.
template <bool RELU_BF16OUT>
__global__ __launch_bounds__(256) void k_agg(const uint2* __restrict__ H,
                                             const int* __restrict__ offsets,
                                             const int* __restrict__ cnt,
                                             const int* __restrict__ csrc,
                                             const float* __restrict__ dinv,
                                             const float* __restrict__ bias,
                                             void* __restrict__ outv, int N) {
    int t = threadIdx.x;
    int lane = t & 63;
    int q = lane >> 4;    // quarter 0..3 -> edge j+q
    int l16 = lane & 15;  // holds features 4*l16 .. 4*l16+3
    int v = blockIdx.x * WPB + (t >> 6);
    if (v >= N) return;
    int beg = offsets[v];
    int deg = cnt[v];
    float a0 = 0.f, a1 = 0.f, a2 = 0.f, a3 = 0.f;
    for (int j = 0; j < deg; j += 4) {
        int e = j + q;
        int s = (e < deg) ? csrc[beg + e] : -1;
        if (s >= 0) {
            uint2 d = H[(size_t)s * 16 + l16];
            a0 += bf16_lo(d.x); a1 += bf16_hi(d.x);
            a2 += bf16_lo(d.y); a3 += bf16_hi(d.y);
        }
    }
    a0 += __shfl_xor(a0, 16); a0 += __shfl_xor(a0, 32);
    a1 += __shfl_xor(a1, 16); a1 += __shfl_xor(a1, 32);
    a2 += __shfl_xor(a2, 16); a2 += __shfl_xor(a2, 32);
    a3 += __shfl_xor(a3, 16); a3 += __shfl_xor(a3, 32);
    if (lane < 16) {
        int f = l16 * 4;
        float dv = dinv[v];
        float r0 = fmaf(dv, a0, bias[f + 0]);
        float r1 = fmaf(dv, a1, bias[f + 1]);
        float r2 = fmaf(dv, a2, bias[f + 2]);
        float r3 = fmaf(dv, a3, bias[f + 3]);
        if (RELU_BF16OUT) {
            r0 = fmaxf(r0, 0.f); r1 = fmaxf(r1, 0.f);
            r2 = fmaxf(r2, 0.f); r3 = fmaxf(r3, 0.f);
            uint2 pk;
            pk.x = bf16_rne(r0) | (bf16_rne(r1) << 16);
            pk.y = bf16_rne(r2) | (bf16_rne(r3) << 16);
            ((uint2*)outv)[(size_t)v * 16 + l16] = pk;
        } else {
            float4 o = make_float4(r0, r1, r2, r3);
            ((float4*)outv)[(size_t)v * 16 + l16] = o;
        }
    }
}

extern "C" void kernel_launch(void* const* d_in, const int* in_sizes, int n_in,
                              void* d_out, int out_size, void* d_ws, size_t ws_size,
                              hipStream_t stream) {
    const float* x  = (const float*)d_in[0];
    const int*   ei = (const int*)d_in[1];  // harness delivers int32
    const float* W1 = (const float*)d_in[2];
    const float* b1 = (const float*)d_in[3];
    const float* W2 = (const float*)d_in[4];
    const float* b2 = (const float*)d_in[5];
    float* out      = (float*)d_out;

    const int N = in_sizes[0] / 64;
    const int E = in_sizes[1] / 2;
    const int* row = ei;
    const int* col = ei + E;
    const int T = E + N;

    char* p = (char*)d_ws;
    auto alloc = [&](size_t bytes) { void* r = (void*)p; p += (bytes + 255) & ~(size_t)255; return r; };
    int*      cnt     = (int*)alloc((size_t)N * 4);
    int*      offsets = (int*)alloc((size_t)N * 4);
    int*      cursor  = (int*)alloc((size_t)N * 4);
    int*      bsum    = (int*)alloc(1024 * 4);
    float*    dinv    = (float*)alloc((size_t)N * 4);
    int*      csrc    = (int*)alloc((size_t)T * 4);
    unsigned* hbuf    = (unsigned*)alloc((size_t)N * 32 * 4);  // bf16 packed
    unsigned* abuf    = (unsigned*)alloc((size_t)N * 32 * 4);  // bf16 packed

    const int B = (N + 1023) / 1024;

    k_init_cnt<<<(N + 255) / 256, 256, 0, stream>>>(cnt, N);
    k_count<<<2048, 256, 0, stream>>>((const int4*)col, E / 4, cnt);
    k_blocksum<<<B, 256, 0, stream>>>(cnt, N, bsum);
    k_scan_bsum<<<1, 256, 0, stream>>>(bsum, B);
    k_scan_chunks<<<B, 256, 0, stream>>>(cnt, N, bsum, offsets, cursor, dinv);
    k_fill<<<2048, 256, 0, stream>>>(row, col, E, N, cursor, csrc);

    const int GEMM_BLOCKS = 1024;
    const int GEMM_WAVES  = GEMM_BLOCKS * WPB;
    const int GB = (N + WPB - 1) / WPB;

    k_gemm<false><<<GEMM_BLOCKS, 256, 0, stream>>>(x, W1, dinv, hbuf, N, GEMM_WAVES);
    k_agg<true><<<GB, 256, 0, stream>>>((const uint2*)hbuf, offsets, cnt, csrc, dinv, b1, abuf, N);
    k_gemm<true><<<GEMM_BLOCKS, 256, 0, stream>>>(abuf, W2, dinv, hbuf, N, GEMM_WAVES);
    k_agg<false><<<GB, 256, 0, stream>>>((const uint2*)hbuf, offsets, cnt, csrc, dinv, b2, out, N);
}